// Round 1
// baseline (868.165 us; speedup 1.0000x reference)
//
#include <hip/hip_runtime.h>
#include <hip/hip_bf16.h>

#define B_  2
#define S_  2048
#define E_  1024
#define H_  16
#define DK_ 64
#define BH_ (B_*H_)   // 32
#define M_  (B_*S_)   // 4096

typedef __attribute__((ext_vector_type(8))) short bf16x8;
typedef __attribute__((ext_vector_type(4))) float f32x4;
typedef unsigned short u16;
typedef unsigned int   u32;

__device__ __forceinline__ float bf2f(u16 u) {
    u32 x = ((u32)u) << 16;
    float f;
    __builtin_memcpy(&f, &x, 4);
    return f;
}
__device__ __forceinline__ u16 f2bf(float f) {
    u32 x;
    __builtin_memcpy(&x, &f, 4);
    u32 r = (x + 0x7fffu + ((x >> 16) & 1u)) >> 16;  // round-to-nearest-even
    return (u16)r;
}

// async 16B global->LDS (lane i lands at lds_base + i*16; dest must be wave-uniform)
__device__ __forceinline__ void async16(const void* g, void* l) {
    __builtin_amdgcn_global_load_lds(
        (__attribute__((address_space(1))) void*)(g),
        (__attribute__((address_space(3))) void*)(l), 16, 0, 0);
}
__device__ __forceinline__ bf16x8 frag_at(const u16* base, int byteoff) {
    return *(const bf16x8*)((const char*)base + byteoff);
}

// read 8 bf16 from LDS -> 8 fp32 global
__device__ __forceinline__ void store8f(float* dst, const u16* src) {
    bf16x8 v = *(const bf16x8*)src;
    float4 lo = {bf2f((u16)v[0]), bf2f((u16)v[1]), bf2f((u16)v[2]), bf2f((u16)v[3])};
    float4 hi = {bf2f((u16)v[4]), bf2f((u16)v[5]), bf2f((u16)v[6]), bf2f((u16)v[7])};
    *(float4*)dst       = lo;
    *(float4*)(dst + 4) = hi;
}

// ---------------------------------------------------------------------------
// Dtype probe: Wq ~ U(-1/32,1/32). If storage is bf16, all u16 decode small.
// ---------------------------------------------------------------------------
__global__ void probe_kernel(const u16* __restrict__ w, int* __restrict__ flag)
{
    if (threadIdx.x == 0 && blockIdx.x == 0) {
        int big = 0;
        for (int i = 0; i < 128; i++) {
            float v = bf2f(w[i]);
            if (fabsf(v) > 0.25f) big++;
        }
        *flag = (big >= 4) ? 1 : 0;   // 1 = fp32 storage
    }
}

// ---------------------------------------------------------------------------
// One-shot dtype normalization: X (3x 4.2M elems) and W (3x 1M elems) -> bf16.
// Moves fp32->bf16 VALU conversion out of the GEMM inner loops.
// ---------------------------------------------------------------------------
__global__ __launch_bounds__(256) void convert_kernel(
    const void* __restrict__ q, const void* __restrict__ k, const void* __restrict__ v,
    const void* __restrict__ wq, const void* __restrict__ wk, const void* __restrict__ wv,
    u16* __restrict__ dq, u16* __restrict__ dk, u16* __restrict__ dv,
    u16* __restrict__ ewq, u16* __restrict__ ewk, u16* __restrict__ ewv,
    const int* __restrict__ flag)
{
    const int y = blockIdx.y;
    const void* src; u16* dst; size_t n;
    switch (y) {
        case 0: src = q;  dst = dq;  n = (size_t)M_*E_; break;
        case 1: src = k;  dst = dk;  n = (size_t)M_*E_; break;
        case 2: src = v;  dst = dv;  n = (size_t)M_*E_; break;
        case 3: src = wq; dst = ewq; n = (size_t)E_*E_; break;
        case 4: src = wk; dst = ewk; n = (size_t)E_*E_; break;
        default:src = wv; dst = ewv; n = (size_t)E_*E_; break;
    }
    const size_t i = ((size_t)blockIdx.x * 256 + threadIdx.x) * 8;
    if (i >= n) return;
    if (*flag) {
        const float* s = (const float*)src + i;
        float4 f0 = *(const float4*)s;
        float4 f1 = *(const float4*)(s + 4);
        u16 tmp[8] = {f2bf(f0.x), f2bf(f0.y), f2bf(f0.z), f2bf(f0.w),
                      f2bf(f1.x), f2bf(f1.y), f2bf(f1.z), f2bf(f1.w)};
        *(uint4*)(dst + i) = *(uint4*)tmp;
    } else {
        *(uint4*)(dst + i) = *(const uint4*)((const u16*)src + i);
    }
}

// ---------------------------------------------------------------------------
// C = X (M x K) * W^T (N x K) + bias. 128x128 tile, BK=64, 4 waves (2x2),
// global_load_lds width-16 with XOR-swizzled SOURCE (linear LDS dest),
// swizzled ds_read_b128 fragment loads (conflict-free: slot ^= (row&7)).
// vmode 0: out[((b*H+h)*S + s)*DK + d]    vmode 1: out[((b*H+h)*DK + d)*S + s]
// ---------------------------------------------------------------------------
__global__ __launch_bounds__(256) void proj_kernel(
    const u16* __restrict__ X, const u16* __restrict__ W,
    const void* __restrict__ biasv, u16* __restrict__ out, int vmode,
    const int* __restrict__ flag)
{
    __shared__ __align__(16) u16 als[128*64];
    __shared__ __align__(16) u16 bls[128*64];
    const int isf32 = *flag;
    const int t    = threadIdx.x;
    const int w    = t >> 6;
    const int ln   = t & 15;
    const int quad = (t >> 4) & 3;
    const int wr   = w >> 1;
    const int wc   = w & 1;
    const int m0   = blockIdx.x * 128;
    const int n0   = blockIdx.y * 128;
    const int l    = t & 63;
    const int srow = l >> 3;                       // 0..7 row within 8-row group
    const int scsw = ((l & 7) * 16) ^ (srow << 4); // swizzled src byte-in-row
    const int rxor = (ln & 7) << 4;                // read-side swizzle

    f32x4 acc[4][4];
    #pragma unroll
    for (int i = 0; i < 4; i++)
        #pragma unroll
        for (int j = 0; j < 4; j++) acc[i][j] = (f32x4){0.f, 0.f, 0.f, 0.f};

    for (int kt = 0; kt < E_; kt += 64) {
        __syncthreads();
        #pragma unroll
        for (int j = 0; j < 4; j++) {
            const int rowa = w*32 + j*8;           // rowa%8==0 -> (row&7)==srow
            async16(&X[(size_t)(m0 + rowa + srow)*E_ + kt + (scsw >> 1)], &als[rowa*64]);
            async16(&W[(size_t)(n0 + rowa + srow)*E_ + kt + (scsw >> 1)], &bls[rowa*64]);
        }
        __syncthreads();
        #pragma unroll
        for (int c = 0; c < 2; c++) {
            const int koff = c*64 + quad*16;
            bf16x8 a[4];
            #pragma unroll
            for (int mf = 0; mf < 4; mf++)
                a[mf] = frag_at(als, (wr*64 + mf*16 + ln)*128 + (koff ^ rxor));
            #pragma unroll
            for (int nf = 0; nf < 4; nf++) {
                bf16x8 b = frag_at(bls, (wc*64 + nf*16 + ln)*128 + (koff ^ rxor));
                #pragma unroll
                for (int mf = 0; mf < 4; mf++)
                    acc[mf][nf] = __builtin_amdgcn_mfma_f32_16x16x32_bf16(a[mf], b, acc[mf][nf], 0, 0, 0);
            }
        }
    }

    #pragma unroll
    for (int nf = 0; nf < 4; nf++) {
        const int n  = n0 + wc*64 + nf*16 + ln;
        const float bv = isf32 ? ((const float*)biasv)[n] : bf2f(((const u16*)biasv)[n]);
        const int h = n >> 6;
        const int d = n & 63;
        #pragma unroll
        for (int mf = 0; mf < 4; mf++) {
            #pragma unroll
            for (int r = 0; r < 4; r++) {
                const int m  = m0 + wr*64 + mf*16 + quad*4 + r;
                const int bb = m >> 11;            // / S_
                const int s  = m & (S_ - 1);
                const float v = acc[mf][nf][r] + bv;
                size_t addr;
                if (vmode == 0) addr = (((size_t)(bb*H_ + h))*S_  + s)*DK_ + d;
                else            addr = (((size_t)(bb*H_ + h))*DK_ + d)*S_  + s;
                out[addr] = f2bf(v);
            }
        }
    }
}

// ---------------------------------------------------------------------------
// RoPE in-place on q (blockIdx.y==0, folds 1/sqrt(DK)=0.125) and k (y==1).
// ---------------------------------------------------------------------------
__global__ __launch_bounds__(256) void rope_kernel(u16* __restrict__ qw, u16* __restrict__ kw)
{
    const int t   = threadIdx.x;
    const int pos = blockIdx.x * 8 + (t >> 5);   // bh*S + s
    const int j   = t & 31;
    const int isq = (blockIdx.y == 0);
    u16* base = (isq ? qw : kw) + (size_t)pos * DK_;
    const int s = pos & (S_ - 1);
    const float scale = isq ? 0.125f : 1.0f;
    if (j < 16) {
        const float invf = powf(10000.0f, -(float)(2*j) / 32.0f);
        const float ang  = (float)s * invf;
        float sn, cs;
        sincosf(ang, &sn, &cs);
        const float x0 = bf2f(base[2*j]);
        const float x1 = bf2f(base[2*j+1]);
        base[2*j]   = f2bf((x0*cs - x1*sn) * scale);
        base[2*j+1] = f2bf((x1*cs + x0*sn) * scale);
    } else if (isq) {
        const int d = j + 16;                    // 32..47
        base[d]      = f2bf(bf2f(base[d])      * 0.125f);
        base[d+16]   = f2bf(bf2f(base[d+16])   * 0.125f);
    }
}

// ---------------------------------------------------------------------------
// Attention. Per block: one (bh, 64-row q tile). Pass 1: rowsum of exp.
// Pass 2: recompute scores, write normalized attn (fp32/bf16), X = P @ V.
// K/V staged via global_load_lds (XOR-swizzled source, linear LDS);
// Q fragments hoisted to registers; bijective XCD swizzle (4 heads per XCD
// -> K+V 2MB resident per XCD L2). LDS 53KB -> 3 blocks/CU.
// ---------------------------------------------------------------------------
__global__ __launch_bounds__(256) void attn_kernel(
    const u16* __restrict__ qw, const u16* __restrict__ kw, const u16* __restrict__ vw,
    void* __restrict__ outbase, const int* __restrict__ flag)
{
    __shared__ __align__(16) u16 qls[64*72];   // padded (one-time frag reads)
    __shared__ __align__(16) u16 pls[64*72];   // [qrow][kpos], padded
    __shared__ __align__(16) u16 kls[64*64];   // linear + XOR swizzle
    __shared__ __align__(16) u16 vls[64*64];   // [d][kpos], linear + XOR swizzle

    const int isf32 = *flag;
    const int t    = threadIdx.x;
    const int id   = blockIdx.y * gridDim.x + blockIdx.x;   // 0..1023
    const int nid  = (id & 7) * 128 + (id >> 3);            // bijective XCD swizzle
    const int bh   = nid >> 5;
    const int q0   = (nid & 31) * 64;
    const int w    = t >> 6;
    const int ln   = t & 15;
    const int quad = (t >> 4) & 3;
    const int lr   = t >> 3;
    const int c8   = (t & 7) * 8;
    const int l    = t & 63;
    const int srow = l >> 3;
    const int scsw = ((l & 7) * 16) ^ (srow << 4);
    const int rxor = (ln & 7) << 4;

    const u16* qb = qw + (size_t)bh * S_ * DK_;
    const u16* kb = kw + (size_t)bh * S_ * DK_;
    const u16* vb = vw + (size_t)bh * DK_ * S_;

    *(uint4*)&qls[lr*72 + c8]      = *(const uint4*)&qb[(size_t)(q0+lr)*DK_    + c8];
    *(uint4*)&qls[(lr+32)*72 + c8] = *(const uint4*)&qb[(size_t)(q0+lr+32)*DK_ + c8];
    __syncthreads();
    bf16x8 qa[2];
    #pragma unroll
    for (int c = 0; c < 2; c++)
        qa[c] = *(const bf16x8*)&qls[(w*16+ln)*72 + c*32 + quad*8];

    // ---------------- pass 1: row sums ----------------
    float rs[4] = {0.f, 0.f, 0.f, 0.f};
    for (int kt = 0; kt < S_; kt += 64) {
        __syncthreads();
        #pragma unroll
        for (int j = 0; j < 2; j++) {
            const int rowa = w*16 + j*8;
            async16(&kb[(size_t)(kt + rowa + srow)*DK_ + (scsw >> 1)], &kls[rowa*64]);
        }
        __syncthreads();
        f32x4 sc[4];
        #pragma unroll
        for (int i = 0; i < 4; i++) sc[i] = (f32x4){0.f, 0.f, 0.f, 0.f};
        #pragma unroll
        for (int c = 0; c < 2; c++) {
            const int koff = c*64 + quad*16;
            #pragma unroll
            for (int cb = 0; cb < 4; cb++) {
                bf16x8 b = frag_at(kls, (cb*16+ln)*128 + (koff ^ rxor));
                sc[cb] = __builtin_amdgcn_mfma_f32_16x16x32_bf16(qa[c], b, sc[cb], 0, 0, 0);
            }
        }
        #pragma unroll
        for (int cb = 0; cb < 4; cb++)
            #pragma unroll
            for (int r = 0; r < 4; r++)
                rs[r] += expf(fminf(sc[cb][r], 60.0f));
    }
    #pragma unroll
    for (int r = 0; r < 4; r++) {
        rs[r] += __shfl_xor(rs[r], 1, 64);
        rs[r] += __shfl_xor(rs[r], 2, 64);
        rs[r] += __shfl_xor(rs[r], 4, 64);
        rs[r] += __shfl_xor(rs[r], 8, 64);
    }
    float inv[4];
    #pragma unroll
    for (int r = 0; r < 4; r++) inv[r] = 1.0f / rs[r];

    // ---------------- pass 2: attn write + PV ----------------
    f32x4 xacc[4];
    #pragma unroll
    for (int i = 0; i < 4; i++) xacc[i] = (f32x4){0.f, 0.f, 0.f, 0.f};

    for (int kt = 0; kt < S_; kt += 64) {
        __syncthreads();
        #pragma unroll
        for (int j = 0; j < 2; j++) {
            const int rowa = w*16 + j*8;
            async16(&kb[(size_t)(kt + rowa + srow)*DK_ + (scsw >> 1)], &kls[rowa*64]);
            async16(&vb[(size_t)(rowa + srow)*S_ + kt + (scsw >> 1)],  &vls[rowa*64]);
        }
        __syncthreads();
        f32x4 sc[4];
        #pragma unroll
        for (int i = 0; i < 4; i++) sc[i] = (f32x4){0.f, 0.f, 0.f, 0.f};
        #pragma unroll
        for (int c = 0; c < 2; c++) {
            const int koff = c*64 + quad*16;
            #pragma unroll
            for (int cb = 0; cb < 4; cb++) {
                bf16x8 b = frag_at(kls, (cb*16+ln)*128 + (koff ^ rxor));
                sc[cb] = __builtin_amdgcn_mfma_f32_16x16x32_bf16(qa[c], b, sc[cb], 0, 0, 0);
            }
        }
        #pragma unroll
        for (int cb = 0; cb < 4; cb++)
            #pragma unroll
            for (int r = 0; r < 4; r++) {
                const float p = expf(fminf(sc[cb][r], 60.0f)) * inv[r];
                pls[(w*16 + quad*4 + r)*72 + cb*16 + ln] = f2bf(p);
            }
        __syncthreads();
        // attn store
        {
            const size_t a0 = ((size_t)bh*S_ + (q0+lr))*S_ + kt + c8;
            const size_t a1 = ((size_t)bh*S_ + (q0+lr+32))*S_ + kt + c8;
            if (isf32) {
                float* af = (float*)outbase + (size_t)M_*E_;
                store8f(&af[a0], &pls[lr*72 + c8]);
                store8f(&af[a1], &pls[(lr+32)*72 + c8]);
            } else {
                u16* au = (u16*)outbase + (size_t)M_*E_;
                *(uint4*)&au[a0] = *(const uint4*)&pls[lr*72 + c8];
                *(uint4*)&au[a1] = *(const uint4*)&pls[(lr+32)*72 + c8];
            }
        }
        // PV: A = P (row-major, padded), B = V^T tile (vls[d][kpos], swizzled)
        #pragma unroll
        for (int c = 0; c < 2; c++) {
            const int koff = c*64 + quad*16;
            bf16x8 pa = *(const bf16x8*)&pls[(w*16+ln)*72 + c*32 + quad*8];
            #pragma unroll
            for (int cb = 0; cb < 4; cb++) {
                bf16x8 b = frag_at(vls, (cb*16+ln)*128 + (koff ^ rxor));
                xacc[cb] = __builtin_amdgcn_mfma_f32_16x16x32_bf16(pa, b, xacc[cb], 0, 0, 0);
            }
        }
    }

    // X epilogue: out[((b*S + s)*H + h)*DK + d]
    const int bb = bh >> 4;
    const int h  = bh & 15;
    #pragma unroll
    for (int cb = 0; cb < 4; cb++) {
        const int d = cb*16 + ln;
        #pragma unroll
        for (int r = 0; r < 4; r++) {
            const int s = q0 + w*16 + quad*4 + r;
            const size_t idx = (((size_t)bb*S_ + s)*H_ + h)*DK_ + d;
            if (isf32) ((float*)outbase)[idx] = xacc[cb][r];
            else       ((u16*)outbase)[idx]   = f2bf(xacc[cb][r]);
        }
    }
}

extern "C" void kernel_launch(void* const* d_in, const int* in_sizes, int n_in,
                              void* d_out, int out_size, void* d_ws, size_t ws_size,
                              hipStream_t stream)
{
    const void* query = d_in[0];
    const void* key   = d_in[1];
    const void* value = d_in[2];
    const void* Wq    = d_in[3];
    const void* bq    = d_in[4];
    const void* Wk    = d_in[5];
    const void* bk    = d_in[6];
    const void* Wv    = d_in[7];
    const void* bv    = d_in[8];

    int* flag = (int*)d_ws;
    u16* qws  = (u16*)((char*)d_ws + 64);        // bf16 (b,h,s,d), 8 MB
    u16* kws  = qws + (size_t)M_ * E_;           // 8 MB
    u16* vws  = kws + (size_t)M_ * E_;           // bf16 (b,h,d,s), 8 MB
    u16* xq   = vws + (size_t)M_ * E_;           // converted inputs, 8 MB each
    u16* xk   = xq  + (size_t)M_ * E_;
    u16* xv   = xk  + (size_t)M_ * E_;
    u16* wqc  = xv  + (size_t)M_ * E_;           // converted weights, 2 MB each
    u16* wkc  = wqc + (size_t)E_ * E_;
    u16* wvc  = wkc + (size_t)E_ * E_;

    probe_kernel<<<1, 64, 0, stream>>>((const u16*)Wq, flag);
    convert_kernel<<<dim3(2048, 6), 256, 0, stream>>>(
        query, key, value, Wq, Wk, Wv, xq, xk, xv, wqc, wkc, wvc, flag);

    dim3 gp(M_/128, E_/128);
    proj_kernel<<<gp, 256, 0, stream>>>(xq, wqc, bq, qws, 0, flag);
    proj_kernel<<<gp, 256, 0, stream>>>(xk, wkc, bk, kws, 0, flag);
    proj_kernel<<<gp, 256, 0, stream>>>(xv, wvc, bv, vws, 1, flag);
    rope_kernel<<<dim3(BH_*S_/8, 2), 256, 0, stream>>>(qws, kws);
    attn_kernel<<<dim3(S_/64, BH_), 256, 0, stream>>>(qws, kws, vws, d_out, flag);
}

// Round 2
// 812.118 us; speedup vs baseline: 1.0690x; 1.0690x over previous
//
#include <hip/hip_runtime.h>
#include <hip/hip_bf16.h>

#define B_  2
#define S_  2048
#define E_  1024
#define H_  16
#define DK_ 64
#define BH_ (B_*H_)   // 32
#define M_  (B_*S_)   // 4096

typedef __attribute__((ext_vector_type(8))) short bf16x8;
typedef __attribute__((ext_vector_type(4))) float f32x4;
typedef unsigned short u16;
typedef unsigned int   u32;

__device__ __forceinline__ float bf2f(u16 u) {
    u32 x = ((u32)u) << 16;
    float f;
    __builtin_memcpy(&f, &x, 4);
    return f;
}
__device__ __forceinline__ u16 f2bf(float f) {
    u32 x;
    __builtin_memcpy(&x, &f, 4);
    u32 r = (x + 0x7fffu + ((x >> 16) & 1u)) >> 16;  // round-to-nearest-even
    return (u16)r;
}

// async 16B global->LDS (lane i lands at lds_base + i*16; dest must be wave-uniform)
__device__ __forceinline__ void async16(const void* g, void* l) {
    __builtin_amdgcn_global_load_lds(
        (__attribute__((address_space(1))) void*)(g),
        (__attribute__((address_space(3))) void*)(l), 16, 0, 0);
}
__device__ __forceinline__ bf16x8 frag_at(const u16* base, int byteoff) {
    return *(const bf16x8*)((const char*)base + byteoff);
}

// read 8 bf16 from LDS -> 8 fp32 global
__device__ __forceinline__ void store8f(float* dst, const u16* src) {
    bf16x8 v = *(const bf16x8*)src;
    float4 lo = {bf2f((u16)v[0]), bf2f((u16)v[1]), bf2f((u16)v[2]), bf2f((u16)v[3])};
    float4 hi = {bf2f((u16)v[4]), bf2f((u16)v[5]), bf2f((u16)v[6]), bf2f((u16)v[7])};
    *(float4*)dst       = lo;
    *(float4*)(dst + 4) = hi;
}

// ---------------------------------------------------------------------------
// Dtype probe: Wq ~ U(-1/32,1/32). If storage is bf16, all u16 decode small.
// ---------------------------------------------------------------------------
__global__ void probe_kernel(const u16* __restrict__ w, int* __restrict__ flag)
{
    if (threadIdx.x == 0 && blockIdx.x == 0) {
        int big = 0;
        for (int i = 0; i < 128; i++) {
            float v = bf2f(w[i]);
            if (fabsf(v) > 0.25f) big++;
        }
        *flag = (big >= 4) ? 1 : 0;   // 1 = fp32 storage
    }
}

// ---------------------------------------------------------------------------
// One-shot dtype normalization: X (3x 4.2M elems) and W (3x 1M elems) -> bf16.
// ---------------------------------------------------------------------------
__global__ __launch_bounds__(256) void convert_kernel(
    const void* __restrict__ q, const void* __restrict__ k, const void* __restrict__ v,
    const void* __restrict__ wq, const void* __restrict__ wk, const void* __restrict__ wv,
    u16* __restrict__ dq, u16* __restrict__ dk, u16* __restrict__ dv,
    u16* __restrict__ ewq, u16* __restrict__ ewk, u16* __restrict__ ewv,
    const int* __restrict__ flag)
{
    const int y = blockIdx.y;
    const void* src; u16* dst; size_t n;
    switch (y) {
        case 0: src = q;  dst = dq;  n = (size_t)M_*E_; break;
        case 1: src = k;  dst = dk;  n = (size_t)M_*E_; break;
        case 2: src = v;  dst = dv;  n = (size_t)M_*E_; break;
        case 3: src = wq; dst = ewq; n = (size_t)E_*E_; break;
        case 4: src = wk; dst = ewk; n = (size_t)E_*E_; break;
        default:src = wv; dst = ewv; n = (size_t)E_*E_; break;
    }
    const size_t i = ((size_t)blockIdx.x * 256 + threadIdx.x) * 8;
    if (i >= n) return;
    if (*flag) {
        const float* s = (const float*)src + i;
        float4 f0 = *(const float4*)s;
        float4 f1 = *(const float4*)(s + 4);
        u16 tmp[8] = {f2bf(f0.x), f2bf(f0.y), f2bf(f0.z), f2bf(f0.w),
                      f2bf(f1.x), f2bf(f1.y), f2bf(f1.z), f2bf(f1.w)};
        *(uint4*)(dst + i) = *(uint4*)tmp;
    } else {
        *(uint4*)(dst + i) = *(const uint4*)((const u16*)src + i);
    }
}

// ---------------------------------------------------------------------------
// Fused QKV projection + RoPE. One dispatch, blockIdx.z selects {q,k,v}.
// C = X (M x K) * W^T (N x K) + bias. 128x128 tile, BK=64, 4 waves (2x2),
// global_load_lds width-16 with XOR-swizzled SOURCE (linear LDS dest),
// swizzled ds_read_b128 fragment loads.
// z=0: q -> rope + 0.125 scale, layout (b,h,s,d)
// z=1: k -> rope,               layout (b,h,s,d)
// z=2: v -> plain,              layout (b,h,d,s)
// RoPE fused in epilogue: pair partner via __shfl_xor(v,1) (lane ln^1 holds
// d^1 of the same row), sincos on fp32 accumulator, single bf16 round.
// ---------------------------------------------------------------------------
__global__ __launch_bounds__(256) void proj_kernel(
    const u16* __restrict__ Xq, const u16* __restrict__ Xk, const u16* __restrict__ Xv,
    const u16* __restrict__ Wqp, const u16* __restrict__ Wkp, const u16* __restrict__ Wvp,
    const void* __restrict__ bqv, const void* __restrict__ bkv, const void* __restrict__ bvv,
    u16* __restrict__ qo, u16* __restrict__ ko, u16* __restrict__ vo,
    const int* __restrict__ flag)
{
    __shared__ __align__(16) u16 als[128*64];
    __shared__ __align__(16) u16 bls[128*64];
    const int isf32 = *flag;
    const int z = blockIdx.z;
    const u16* X = (z==0) ? Xq  : ((z==1) ? Xk  : Xv);
    const u16* W = (z==0) ? Wqp : ((z==1) ? Wkp : Wvp);
    const void* biasv = (z==0) ? bqv : ((z==1) ? bkv : bvv);
    u16* out = (z==0) ? qo : ((z==1) ? ko : vo);

    const int t    = threadIdx.x;
    const int w    = t >> 6;
    const int ln   = t & 15;
    const int quad = (t >> 4) & 3;
    const int wr   = w >> 1;
    const int wc   = w & 1;
    const int m0   = blockIdx.x * 128;
    const int n0   = blockIdx.y * 128;
    const int l    = t & 63;
    const int srow = l >> 3;                       // row within 8-row group
    const int scsw = ((l & 7) * 16) ^ (srow << 4); // swizzled src byte-in-row
    const int rxor = (ln & 7) << 4;                // read-side swizzle

    f32x4 acc[4][4];
    #pragma unroll
    for (int i = 0; i < 4; i++)
        #pragma unroll
        for (int j = 0; j < 4; j++) acc[i][j] = (f32x4){0.f, 0.f, 0.f, 0.f};

    for (int kt = 0; kt < E_; kt += 64) {
        __syncthreads();
        #pragma unroll
        for (int j = 0; j < 4; j++) {
            const int rowa = w*32 + j*8;
            async16(&X[(size_t)(m0 + rowa + srow)*E_ + kt + (scsw >> 1)], &als[rowa*64]);
            async16(&W[(size_t)(n0 + rowa + srow)*E_ + kt + (scsw >> 1)], &bls[rowa*64]);
        }
        __syncthreads();
        #pragma unroll
        for (int c = 0; c < 2; c++) {
            const int koff = c*64 + quad*16;
            bf16x8 a[4];
            #pragma unroll
            for (int mf = 0; mf < 4; mf++)
                a[mf] = frag_at(als, (wr*64 + mf*16 + ln)*128 + (koff ^ rxor));
            #pragma unroll
            for (int nf = 0; nf < 4; nf++) {
                bf16x8 b = frag_at(bls, (wc*64 + nf*16 + ln)*128 + (koff ^ rxor));
                #pragma unroll
                for (int mf = 0; mf < 4; mf++)
                    acc[mf][nf] = __builtin_amdgcn_mfma_f32_16x16x32_bf16(a[mf], b, acc[mf][nf], 0, 0, 0);
            }
        }
    }

    const float scale = (z == 0) ? 0.125f : 1.0f;   // fold 1/sqrt(DK) into q
    #pragma unroll
    for (int nf = 0; nf < 4; nf++) {
        const int n  = n0 + wc*64 + nf*16 + ln;
        const float bvf = isf32 ? ((const float*)biasv)[n] : bf2f(((const u16*)biasv)[n]);
        const int h = n >> 6;
        const int d = n & 63;
        const int dorope = (z <= 1) && (d < 32);   // uniform per nf (d = nf*16+ln)
        const float sgn  = (d & 1) ? 1.0f : -1.0f;
        float invf = 0.f;
        if (dorope) invf = powf(10000.0f, -(float)(d & ~1) / 32.0f);
        #pragma unroll
        for (int mf = 0; mf < 4; mf++) {
            #pragma unroll
            for (int r = 0; r < 4; r++) {
                const int m  = m0 + wr*64 + mf*16 + quad*4 + r;
                const int bb = m >> 11;            // / S_
                const int s  = m & (S_ - 1);
                float v = acc[mf][nf][r] + bvf;
                if (dorope) {
                    const float vp = __shfl_xor(v, 1, 64);  // partner d^1, same row
                    float sn, cs;
                    sincosf((float)s * invf, &sn, &cs);
                    v = v*cs + sgn*vp*sn;          // even d: x*c - x1*s; odd: x*c + x0*s
                }
                v *= scale;
                size_t addr;
                if (z == 2) addr = (((size_t)(bb*H_ + h))*DK_ + d)*S_  + s;
                else        addr = (((size_t)(bb*H_ + h))*S_  + s)*DK_ + d;
                out[addr] = f2bf(v);
            }
        }
    }
}

// ---------------------------------------------------------------------------
// Attention. QBLK=128 per block (4 waves, each owns 32 q-rows -> 16 MFMA per
// wave per barrier phase in QK^T, 32 in pass 2). Two passes: rowsum, then
// normalize + attn store + PV. K/V via global_load_lds (swizzled source,
// linear LDS dest, swizzled ds_read). Q staged once, frags hoisted to regs
// (sstage reused as the K tile buffer). Bijective XCD swizzle: 4 heads/XCD
// so K+V (2 MB) stays L2-resident. LDS 43 KB -> 3 blocks/CU.
// ---------------------------------------------------------------------------
__global__ __launch_bounds__(256) void attn_kernel(
    const u16* __restrict__ qw, const u16* __restrict__ kw, const u16* __restrict__ vw,
    void* __restrict__ outbase, const int* __restrict__ flag)
{
    __shared__ __align__(16) u16 sstage[128*64];  // Q stage, then K tiles (first 8 KB)
    __shared__ __align__(16) u16 vls[64*64];      // [d][kpos]
    __shared__ __align__(16) u16 pls[128*72];     // [qrow][kpos], padded

    const int isf32 = *flag;
    const int t    = threadIdx.x;
    const int id   = blockIdx.y * gridDim.x + blockIdx.x;   // 0..511
    const int nid  = (id & 7) * 64 + (id >> 3);             // bijective XCD swizzle
    const int bh   = nid >> 4;
    const int q0   = (nid & 15) * 128;
    const int w    = t >> 6;
    const int ln   = t & 15;
    const int quad = (t >> 4) & 3;
    const int lr   = t >> 3;      // 0..31
    const int c8   = (t & 7) * 8;
    const int l    = t & 63;
    const int srow = l >> 3;
    const int scsw = ((l & 7) * 16) ^ (srow << 4);
    const int rxor = (ln & 7) << 4;

    const u16* qb = qw + (size_t)bh * S_ * DK_;
    const u16* kb = kw + (size_t)bh * S_ * DK_;
    const u16* vb = vw + (size_t)bh * DK_ * S_;

    // stage Q (128x64 bf16), hoist fragments, then recycle sstage for K
    #pragma unroll
    for (int j = 0; j < 4; j++) {
        const int rowa = w*32 + j*8;
        async16(&qb[(size_t)(q0 + rowa + srow)*DK_ + (scsw >> 1)], &sstage[rowa*64]);
    }
    __syncthreads();
    bf16x8 qa[2][2];
    #pragma unroll
    for (int m = 0; m < 2; m++)
        #pragma unroll
        for (int c = 0; c < 2; c++)
            qa[m][c] = frag_at(sstage, (w*32 + m*16 + ln)*128 + ((c*64 + quad*16) ^ rxor));

    // ---------------- pass 1: row sums ----------------
    float rs[2][4];
    #pragma unroll
    for (int m = 0; m < 2; m++)
        #pragma unroll
        for (int r = 0; r < 4; r++) rs[m][r] = 0.f;

    for (int kt = 0; kt < S_; kt += 64) {
        __syncthreads();
        #pragma unroll
        for (int j = 0; j < 2; j++) {
            const int rowa = w*16 + j*8;
            async16(&kb[(size_t)(kt + rowa + srow)*DK_ + (scsw >> 1)], &sstage[rowa*64]);
        }
        __syncthreads();
        f32x4 sc[2][4];
        #pragma unroll
        for (int m = 0; m < 2; m++)
            #pragma unroll
            for (int cb = 0; cb < 4; cb++) sc[m][cb] = (f32x4){0.f, 0.f, 0.f, 0.f};
        #pragma unroll
        for (int c = 0; c < 2; c++) {
            const int koff = c*64 + quad*16;
            #pragma unroll
            for (int cb = 0; cb < 4; cb++) {
                bf16x8 b = frag_at(sstage, (cb*16+ln)*128 + (koff ^ rxor));
                #pragma unroll
                for (int m = 0; m < 2; m++)
                    sc[m][cb] = __builtin_amdgcn_mfma_f32_16x16x32_bf16(qa[m][c], b, sc[m][cb], 0, 0, 0);
            }
        }
        #pragma unroll
        for (int m = 0; m < 2; m++)
            #pragma unroll
            for (int cb = 0; cb < 4; cb++)
                #pragma unroll
                for (int r = 0; r < 4; r++)
                    rs[m][r] += expf(fminf(sc[m][cb][r], 60.0f));
    }
    float inv[2][4];
    #pragma unroll
    for (int m = 0; m < 2; m++)
        #pragma unroll
        for (int r = 0; r < 4; r++) {
            float x = rs[m][r];
            x += __shfl_xor(x, 1, 64);
            x += __shfl_xor(x, 2, 64);
            x += __shfl_xor(x, 4, 64);
            x += __shfl_xor(x, 8, 64);
            inv[m][r] = 1.0f / x;
        }

    // ---------------- pass 2: attn write + PV ----------------
    f32x4 xacc[2][4];
    #pragma unroll
    for (int m = 0; m < 2; m++)
        #pragma unroll
        for (int cb = 0; cb < 4; cb++) xacc[m][cb] = (f32x4){0.f, 0.f, 0.f, 0.f};

    for (int kt = 0; kt < S_; kt += 64) {
        __syncthreads();
        #pragma unroll
        for (int j = 0; j < 2; j++) {
            const int rowa = w*16 + j*8;
            async16(&kb[(size_t)(kt + rowa + srow)*DK_ + (scsw >> 1)], &sstage[rowa*64]);
            async16(&vb[(size_t)(rowa + srow)*S_ + kt + (scsw >> 1)],  &vls[rowa*64]);
        }
        __syncthreads();
        f32x4 sc[2][4];
        #pragma unroll
        for (int m = 0; m < 2; m++)
            #pragma unroll
            for (int cb = 0; cb < 4; cb++) sc[m][cb] = (f32x4){0.f, 0.f, 0.f, 0.f};
        #pragma unroll
        for (int c = 0; c < 2; c++) {
            const int koff = c*64 + quad*16;
            #pragma unroll
            for (int cb = 0; cb < 4; cb++) {
                bf16x8 b = frag_at(sstage, (cb*16+ln)*128 + (koff ^ rxor));
                #pragma unroll
                for (int m = 0; m < 2; m++)
                    sc[m][cb] = __builtin_amdgcn_mfma_f32_16x16x32_bf16(qa[m][c], b, sc[m][cb], 0, 0, 0);
            }
        }
        #pragma unroll
        for (int m = 0; m < 2; m++)
            #pragma unroll
            for (int cb = 0; cb < 4; cb++)
                #pragma unroll
                for (int r = 0; r < 4; r++) {
                    const float p = expf(fminf(sc[m][cb][r], 60.0f)) * inv[m][r];
                    pls[(w*32 + m*16 + quad*4 + r)*72 + cb*16 + ln] = f2bf(p);
                }
        __syncthreads();
        // attn store (issue vmem first, PV MFMAs overlap the stores)
        #pragma unroll
        for (int rep = 0; rep < 4; rep++) {
            const int row = lr + rep*32;
            const size_t a = ((size_t)bh*S_ + (q0 + row))*S_ + kt + c8;
            if (isf32) store8f((float*)outbase + (size_t)M_*E_ + a, &pls[row*72 + c8]);
            else       *(uint4*)((u16*)outbase + (size_t)M_*E_ + a) = *(const uint4*)&pls[row*72 + c8];
        }
        // PV: A = P own rows (padded), B = V^T tile (vls[d][kpos], swizzled)
        #pragma unroll
        for (int c = 0; c < 2; c++) {
            const int koff = c*64 + quad*16;
            bf16x8 pa[2];
            #pragma unroll
            for (int m = 0; m < 2; m++)
                pa[m] = *(const bf16x8*)&pls[(w*32 + m*16 + ln)*72 + c*32 + quad*8];
            #pragma unroll
            for (int cb = 0; cb < 4; cb++) {
                bf16x8 b = frag_at(vls, (cb*16+ln)*128 + (koff ^ rxor));
                #pragma unroll
                for (int m = 0; m < 2; m++)
                    xacc[m][cb] = __builtin_amdgcn_mfma_f32_16x16x32_bf16(pa[m], b, xacc[m][cb], 0, 0, 0);
            }
        }
    }

    // X epilogue: out[((b*S + s)*H + h)*DK + d]
    const int bb = bh >> 4;
    const int h  = bh & 15;
    #pragma unroll
    for (int m = 0; m < 2; m++)
        #pragma unroll
        for (int cb = 0; cb < 4; cb++) {
            const int d = cb*16 + ln;
            #pragma unroll
            for (int r = 0; r < 4; r++) {
                const int s = q0 + w*32 + m*16 + quad*4 + r;
                const size_t idx = (((size_t)bb*S_ + s)*H_ + h)*DK_ + d;
                if (isf32) ((float*)outbase)[idx] = xacc[m][cb][r];
                else       ((u16*)outbase)[idx]   = f2bf(xacc[m][cb][r]);
            }
        }
}

extern "C" void kernel_launch(void* const* d_in, const int* in_sizes, int n_in,
                              void* d_out, int out_size, void* d_ws, size_t ws_size,
                              hipStream_t stream)
{
    const void* query = d_in[0];
    const void* key   = d_in[1];
    const void* value = d_in[2];
    const void* Wq    = d_in[3];
    const void* bq    = d_in[4];
    const void* Wk    = d_in[5];
    const void* bk    = d_in[6];
    const void* Wv    = d_in[7];
    const void* bv    = d_in[8];

    int* flag = (int*)d_ws;
    u16* qws  = (u16*)((char*)d_ws + 64);        // bf16 (b,h,s,d), 8 MB
    u16* kws  = qws + (size_t)M_ * E_;           // 8 MB
    u16* vws  = kws + (size_t)M_ * E_;           // bf16 (b,h,d,s), 8 MB
    u16* xq   = vws + (size_t)M_ * E_;           // converted inputs, 8 MB each
    u16* xk   = xq  + (size_t)M_ * E_;
    u16* xv   = xk  + (size_t)M_ * E_;
    u16* wqc  = xv  + (size_t)M_ * E_;           // converted weights, 2 MB each
    u16* wkc  = wqc + (size_t)E_ * E_;
    u16* wvc  = wkc + (size_t)E_ * E_;

    probe_kernel<<<1, 64, 0, stream>>>((const u16*)Wq, flag);
    convert_kernel<<<dim3(2048, 6), 256, 0, stream>>>(
        query, key, value, Wq, Wk, Wv, xq, xk, xv, wqc, wkc, wvc, flag);

    proj_kernel<<<dim3(M_/128, E_/128, 3), 256, 0, stream>>>(
        xq, xk, xv, wqc, wkc, wvc, bq, bk, bv, qws, kws, vws, flag);

    attn_kernel<<<dim3(S_/128, BH_), 256, 0, stream>>>(qws, kws, vws, d_out, flag);
}